// Round 4
// baseline (266.914 us; speedup 1.0000x reference)
//
#include <hip/hip_runtime.h>
#include <hip/hip_bf16.h>
#include <math.h>

typedef __bf16 bf16_t;
typedef __bf16 bf16x4_t __attribute__((ext_vector_type(4)));
typedef __bf16 bf16x8 __attribute__((ext_vector_type(8)));
typedef float f32x4 __attribute__((ext_vector_type(4)));
typedef unsigned long long u64;

#define NB 1024
#define NN 75
#define KF 512
#define F1 256
#define HCH 40     // hT chunk row stride (bf16): 32 j + 8 pad, 16B-aligned rows
#define ASTR 100   // alp row stride (bf16): 50 dwords -> 16 distinct bank starts

// ---------------------------------------------------------------------------
// Kernel 0: W [512][256] fp32 -> Wt [256][512] bf16 (transposed, k-contiguous)
// ---------------------------------------------------------------------------
__global__ __launch_bounds__(256) void wt_kernel(const float* __restrict__ W,
                                                 bf16_t* __restrict__ Wt) {
    __shared__ float tile[64][65];
    const int kb = blockIdx.x * 64;
    const int nb = blockIdx.y * 64;
    const int tc = threadIdx.x & 63;
    const int tr = threadIdx.x >> 6;
#pragma unroll
    for (int r = tr; r < 64; r += 4)
        tile[r][tc] = W[(size_t)(kb + r) * F1 + nb + tc];
    __syncthreads();
#pragma unroll
    for (int r = tr; r < 64; r += 4)
        Wt[(size_t)(nb + r) * KF + kb + tc] = (bf16_t)tile[tc][r];
}

// ---------------------------------------------------------------------------
// Fused: one block per batch, 4 waves, 3 blocks/CU.
//  G: h = X[b]@Wt, A/B frags direct from global (no LDS, no barriers)
//  T: h->out[...,256:512]; pack hbf; att partials via shfl
//  S: 4-lane-group masked softmax (bitmask adjacency), unnormalized alp
//  P: out[...,0:256] = (alp @ h) * rs via MFMA over 3 k-chunks of 32
// ---------------------------------------------------------------------------
__global__ __launch_bounds__(256, 3) void fused_kernel(
    const float* __restrict__ X, const bf16_t* __restrict__ Wt,
    const int* __restrict__ Adj, const float* __restrict__ avec,
    float* __restrict__ out) {

    __shared__ __align__(16) char smem[43328];
    bf16_t* hT    = (bf16_t*)smem;                  // [256][HCH]  20480 B
    bf16_t* alp   = (bf16_t*)(smem + 20480);        // [80][ASTR]  16000 B
    float*  attp  = (float*)(smem + 36480);         // [8][80]      2560 B
    u64*    adjb  = (u64*)(smem + 39040);           // [80][2]      1280 B
    float*  a0s   = (float*)(smem + 40320);         // [256]        1024 B
    float*  a1s   = (float*)(smem + 41344);         // [256]        1024 B
    float*  att0s = (float*)(smem + 42368);         // [80]          320 B
    float*  att1s = (float*)(smem + 42688);         // [80]          320 B
    float*  rsums = (float*)(smem + 43008);         // [80]          320 B

    const int b = blockIdx.x;
    const int t = threadIdx.x;
    const int w = t >> 6;
    const int l = t & 63;
    const int lc = l & 15;
    const int lr = l >> 4;
    const float* Xb = X + (size_t)b * NN * KF;
    float* outb = out + (size_t)b * NN * 512;

    a0s[t] = avec[t];
    a1s[t] = avec[F1 + t];

    // ---- adjacency bitmask (built once, L2-hot loads) ----
    for (int i = w; i < NN; i += 4) {
        const int v0 = Adj[i * NN + l];
        const int v1 = (l < NN - 64) ? Adj[i * NN + 64 + l] : 0;
        const u64 b0 = __ballot(v0 != 0);
        const u64 b1 = __ballot(v1 != 0);
        if (l == 0) { adjb[i * 2] = b0; adjb[i * 2 + 1] = b1; }
    }

    // ---- phase G: h = X@Wt, fragments direct from global ----
    f32x4 acc[5][4];
#pragma unroll
    for (int i = 0; i < 5; ++i)
#pragma unroll
        for (int j = 0; j < 4; ++j) acc[i][j] = (f32x4){0.f, 0.f, 0.f, 0.f};

    float4 xr[5][2];
    bf16x8 wb[4];
#pragma unroll
    for (int mt = 0; mt < 5; ++mt) {
        xr[mt][0] = (float4){0.f, 0.f, 0.f, 0.f};
        xr[mt][1] = (float4){0.f, 0.f, 0.f, 0.f};
        const int row = mt * 16 + lc;
        if (row < NN) {
            const float* p = Xb + (size_t)row * KF + lr * 8;
            xr[mt][0] = *(const float4*)p;
            xr[mt][1] = *(const float4*)(p + 4);
        }
    }
#pragma unroll
    for (int p = 0; p < 4; ++p)
        wb[p] = *(const bf16x8*)(Wt + (size_t)(w * 64 + p * 16 + lc) * KF + lr * 8);

    for (int ks = 0; ks < 16; ++ks) {
        const int k1 = (ks + 1) * 32;
#pragma unroll
        for (int mt = 0; mt < 5; ++mt) {
            bf16x8 af;
            af[0] = (bf16_t)xr[mt][0].x; af[1] = (bf16_t)xr[mt][0].y;
            af[2] = (bf16_t)xr[mt][0].z; af[3] = (bf16_t)xr[mt][0].w;
            af[4] = (bf16_t)xr[mt][1].x; af[5] = (bf16_t)xr[mt][1].y;
            af[6] = (bf16_t)xr[mt][1].z; af[7] = (bf16_t)xr[mt][1].w;
            if (ks < 15) {
                const int row = mt * 16 + lc;
                if (row < NN) {
                    const float* p = Xb + (size_t)row * KF + k1 + lr * 8;
                    xr[mt][0] = *(const float4*)p;
                    xr[mt][1] = *(const float4*)(p + 4);
                }
            }
#pragma unroll
            for (int ntl = 0; ntl < 4; ++ntl)
                acc[mt][ntl] = __builtin_amdgcn_mfma_f32_16x16x32_bf16(af, wb[ntl], acc[mt][ntl], 0, 0, 0);
        }
        if (ks < 15) {
#pragma unroll
            for (int p = 0; p < 4; ++p)
                wb[p] = *(const bf16x8*)(Wt + (size_t)(w * 64 + p * 16 + lc) * KF + k1 + lr * 8);
        }
    }

    __syncthreads();   // a0s/a1s/adjb visibility

    // ---- phase T: h stores, att partials, pack hbf ----
    float a0c[4], a1c[4];
#pragma unroll
    for (int ntl = 0; ntl < 4; ++ntl) {
        a0c[ntl] = a0s[w * 64 + ntl * 16 + lc];
        a1c[ntl] = a1s[w * 64 + ntl * 16 + lc];
    }
    float p0[5][4], p1[5][4];
#pragma unroll
    for (int mt = 0; mt < 5; ++mt)
#pragma unroll
        for (int j = 0; j < 4; ++j) { p0[mt][j] = 0.f; p1[mt][j] = 0.f; }

    bf16x4_t hbf[5][4];
#pragma unroll
    for (int mt = 0; mt < 5; ++mt) {
#pragma unroll
        for (int ntl = 0; ntl < 4; ++ntl) {
            const f32x4 v = acc[mt][ntl];
            const int ch = w * 64 + ntl * 16 + lc;
#pragma unroll
            for (int j = 0; j < 4; ++j) {
                const int row = mt * 16 + lr * 4 + j;
                if (row < NN) outb[(size_t)row * 512 + 256 + ch] = v[j];
                p0[mt][j] += v[j] * a0c[ntl];
                p1[mt][j] += v[j] * a1c[ntl];
            }
            bf16x4_t hv;
            hv[0] = (bf16_t)v[0]; hv[1] = (bf16_t)v[1];
            hv[2] = (bf16_t)v[2]; hv[3] = (bf16_t)v[3];
            hbf[mt][ntl] = hv;
        }
    }
#pragma unroll
    for (int off = 1; off < 16; off <<= 1) {
#pragma unroll
        for (int mt = 0; mt < 5; ++mt)
#pragma unroll
            for (int j = 0; j < 4; ++j) {
                p0[mt][j] += __shfl_xor(p0[mt][j], off);
                p1[mt][j] += __shfl_xor(p1[mt][j], off);
            }
    }
    if (lc == 0) {
#pragma unroll
        for (int mt = 0; mt < 5; ++mt)
#pragma unroll
            for (int j = 0; j < 4; ++j) {
                attp[w * 80 + mt * 16 + lr * 4 + j]       = p0[mt][j];
                attp[(4 + w) * 80 + mt * 16 + lr * 4 + j] = p1[mt][j];
            }
    }
    __syncthreads();

    // ---- phase 1b: wave-sum partials; zero alp pad region ----
    if (t < 80)
        att0s[t] = attp[t] + attp[80 + t] + attp[160 + t] + attp[240 + t];
    else if (t < 160)
        att1s[t - 80] = attp[320 + t - 80] + attp[400 + t - 80] + attp[480 + t - 80] + attp[560 + t - 80];
    else if (t < 240) {
        const int r = t - 160;
        if (r < NN) {
            for (int c = NN; c < 96; ++c) alp[r * ASTR + c] = (bf16_t)0.f;
        } else {
            for (int c = 0; c < 96; ++c) alp[r * ASTR + c] = (bf16_t)0.f;
        }
    }
    __syncthreads();

    // ---- phase S: 4-lane-group masked softmax (unnormalized) ----
    {
        const int gid = t >> 2;
        const int k4 = t & 3;
        for (int r = 0; r < 2; ++r) {
            const int i = r * 64 + gid;
            if (i < NN) {
                const float a0i = att0s[i];
                const u64 w0 = adjb[i * 2];
                const u64 w1 = adjb[i * 2 + 1];
                float e[19];
                float m = -3.0e38f;
#pragma unroll
                for (int jj = 0; jj < 19; ++jj) {
                    const int j = jj * 4 + k4;
                    float ev = -3.0e38f;
                    if (j < NN) {
                        float x = a0i + att1s[j];
                        x = x > 0.f ? x : 0.2f * x;
                        const u64 wj = (j < 64) ? w0 : w1;
                        const int bit = (int)((wj >> (j & 63)) & 1);
                        ev = bit ? x : x - 1.0e9f;
                    }
                    e[jj] = ev;
                    m = fmaxf(m, ev);
                }
                m = fmaxf(m, __shfl_xor(m, 1));
                m = fmaxf(m, __shfl_xor(m, 2));
                float s = 0.f;
#pragma unroll
                for (int jj = 0; jj < 19; ++jj) {
                    const int j = jj * 4 + k4;
                    if (j < NN) {
                        const float ex = __expf(e[jj] - m);
                        s += ex;
                        alp[i * ASTR + j] = (bf16_t)ex;
                    }
                }
                s += __shfl_xor(s, 1);
                s += __shfl_xor(s, 2);
                if (k4 == 0) rsums[i] = 1.f / s;
            }
        }
    }
    __syncthreads();

    // ---- phase P: out = (alp @ h) * rs via MFMA, 3 k-chunks ----
    f32x4 acc2[5][4];
#pragma unroll
    for (int i = 0; i < 5; ++i)
#pragma unroll
        for (int j = 0; j < 4; ++j) acc2[i][j] = (f32x4){0.f, 0.f, 0.f, 0.f};

#pragma unroll
    for (int kc = 0; kc < 3; ++kc) {
#pragma unroll
        for (int g = 0; g < 2; ++g) {
            const int mt = kc * 2 + g;
#pragma unroll
            for (int ntl = 0; ntl < 4; ++ntl) {
                const int ch = w * 64 + ntl * 16 + lc;
                bf16x4_t v;
                if (mt < 5) {
                    v = hbf[mt][ntl];
                } else {
                    v[0] = (bf16_t)0.f; v[1] = (bf16_t)0.f;
                    v[2] = (bf16_t)0.f; v[3] = (bf16_t)0.f;
                }
                *(bf16x4_t*)&hT[ch * HCH + g * 16 + lr * 4] = v;
            }
        }
        __syncthreads();
        bf16x8 bv[4];
#pragma unroll
        for (int ntl = 0; ntl < 4; ++ntl)
            bv[ntl] = *(const bf16x8*)&hT[(w * 64 + ntl * 16 + lc) * HCH + lr * 8];
#pragma unroll
        for (int mt = 0; mt < 5; ++mt) {
            const bf16_t* ap = &alp[(mt * 16 + lc) * ASTR + kc * 32 + lr * 8];
            bf16x8 av;
            ((uint2*)&av)[0] = *(const uint2*)ap;
            ((uint2*)&av)[1] = *(const uint2*)(ap + 4);
#pragma unroll
            for (int ntl = 0; ntl < 4; ++ntl)
                acc2[mt][ntl] = __builtin_amdgcn_mfma_f32_16x16x32_bf16(av, bv[ntl], acc2[mt][ntl], 0, 0, 0);
        }
        if (kc < 2) __syncthreads();
    }

    // epilogue: scale by 1/s and store
#pragma unroll
    for (int mt = 0; mt < 5; ++mt) {
        float rsv[4];
#pragma unroll
        for (int j = 0; j < 4; ++j) {
            const int row = mt * 16 + lr * 4 + j;
            rsv[j] = (row < NN) ? rsums[row] : 0.f;
        }
#pragma unroll
        for (int ntl = 0; ntl < 4; ++ntl) {
            const int ch = w * 64 + ntl * 16 + lc;
#pragma unroll
            for (int j = 0; j < 4; ++j) {
                const int row = mt * 16 + lr * 4 + j;
                if (row < NN) outb[(size_t)row * 512 + ch] = acc2[mt][ntl][j] * rsv[j];
            }
        }
    }
}

// ---------------------------------------------------------------------------
extern "C" void kernel_launch(void* const* d_in, const int* in_sizes, int n_in,
                              void* d_out, int out_size, void* d_ws, size_t ws_size,
                              hipStream_t stream) {
    const float* X = (const float*)d_in[0];   // [1024,75,512] f32
    const int*   A = (const int*)d_in[1];     // [75,75] i32
    const float* W = (const float*)d_in[2];   // [512,256] f32
    const float* a = (const float*)d_in[3];   // [2,256,1] f32
    float* out = (float*)d_out;               // [1024,75,512] f32
    bf16_t* Wt = (bf16_t*)d_ws;               // 256 KB scratch

    wt_kernel<<<dim3(KF / 64, F1 / 64), 256, 0, stream>>>(W, Wt);
    fused_kernel<<<NB, 256, 0, stream>>>(X, Wt, A, a, out);
}

// Round 5
// 159.619 us; speedup vs baseline: 1.6722x; 1.6722x over previous
//
#include <hip/hip_runtime.h>
#include <hip/hip_bf16.h>
#include <math.h>

typedef __bf16 bf16_t;
typedef __bf16 bf16x4_t __attribute__((ext_vector_type(4)));
typedef __bf16 bf16x8 __attribute__((ext_vector_type(8)));
typedef float f32x4 __attribute__((ext_vector_type(4)));
typedef unsigned long long u64;

#define NB 1024
#define NN 75
#define KF 512
#define F1 256
#define XSTR 40     // X tile row stride (bf16): 32 + 8 pad (80B rows -> 2-way-free banks)
#define XSLOT (80 * XSTR)   // elems per ring slot (6400 B)
#define HCH 40      // hT chunk row stride
#define ASTR 100    // alp row stride (bf16)

// ---------------------------------------------------------------------------
// Kernel 0: W [512][256] fp32 -> Wt [256][512] bf16 (transposed, k-contiguous)
// ---------------------------------------------------------------------------
__global__ __launch_bounds__(256) void wt_kernel(const float* __restrict__ W,
                                                 bf16_t* __restrict__ Wt) {
    __shared__ float tile[64][65];
    const int kb = blockIdx.x * 64;
    const int nb = blockIdx.y * 64;
    const int tc = threadIdx.x & 63;
    const int tr = threadIdx.x >> 6;
#pragma unroll
    for (int r = tr; r < 64; r += 4)
        tile[r][tc] = W[(size_t)(kb + r) * F1 + nb + tc];
    __syncthreads();
#pragma unroll
    for (int r = tr; r < 64; r += 4)
        Wt[(size_t)(nb + r) * KF + kb + tc] = (bf16_t)tile[tc][r];
}

// ---------------------------------------------------------------------------
// Fused: one block per batch, 4 waves, 3 blocks/CU (48.4 KB LDS).
//  G: h = X[b]@Wt. X ring-4 LDS staged (issue k+2 / write k+1 / read k),
//     W frags direct from L2-hot Wt. 1 barrier per K-step.
//  T: h->out[...,256:512]; pack hbf regs; att partials via shfl
//  S: 4-lane-group masked softmax (bitmask adjacency), unnormalized alp
//  P: out[...,0:256] = (alp @ h) * rs via MFMA over 3 k-chunks of 32
// ---------------------------------------------------------------------------
__global__ __launch_bounds__(256, 3) void fused_kernel(
    const float* __restrict__ X, const bf16_t* __restrict__ Wt,
    const int* __restrict__ Adj, const float* __restrict__ avec,
    float* __restrict__ out) {

    __shared__ __align__(16) char smem[48448];
    bf16_t* Xs    = (bf16_t*)smem;                  // ring 4 x [80][XSTR] = 25600 B
    bf16_t* hT    = (bf16_t*)smem;                  // [256][HCH] 20480 B (union w/ Xs)
    bf16_t* alp   = (bf16_t*)(smem + 25600);        // [80][ASTR] 16000 B
    float*  attp  = (float*)(smem + 41600);         // [8][80]     2560 B
    u64*    adjb  = (u64*)(smem + 44160);           // [80][2]     1280 B
    float*  a0s   = (float*)(smem + 45440);         // [256]       1024 B
    float*  a1s   = (float*)(smem + 46464);         // [256]       1024 B
    float*  att0s = (float*)(smem + 47488);         // [80]         320 B
    float*  att1s = (float*)(smem + 47808);         // [80]         320 B
    float*  rsums = (float*)(smem + 48128);         // [80]         320 B

    const int b = blockIdx.x;
    const int t = threadIdx.x;
    const int w = t >> 6;
    const int l = t & 63;
    const int lc = l & 15;
    const int lr = l >> 4;
    const float* Xb = X + (size_t)b * NN * KF;
    float* outb = out + (size_t)b * NN * 512;

    a0s[t] = avec[t];
    a1s[t] = avec[F1 + t];

    // ---- adjacency bitmask ----
    for (int i = w; i < NN; i += 4) {
        const int v0 = Adj[i * NN + l];
        const int v1 = (l < NN - 64) ? Adj[i * NN + 64 + l] : 0;
        const u64 b0 = __ballot(v0 != 0);
        const u64 b1 = __ballot(v1 != 0);
        if (l == 0) { adjb[i * 2] = b0; adjb[i * 2 + 1] = b1; }
    }

    // staging coords: thread t stages row t>>2 (+ row 64+(t>>2) if t<64), chunk (t&3)*8
    const int xrow0 = t >> 2;
    const int xkc   = (t & 3) * 8;
    const int xrow1 = 64 + (t >> 2);
    const bool has1 = (t < 64);
    const bool live1 = has1 && (xrow1 < NN);

    f32x4 acc[5][4];
#pragma unroll
    for (int i = 0; i < 5; ++i)
#pragma unroll
        for (int j = 0; j < 4; ++j) acc[i][j] = (f32x4){0.f, 0.f, 0.f, 0.f};

    // in-flight X registers: O = data for step k+1, N = data for step k+2
    float4 o0a, o0b, o1a, o1b, n0a, n0b, n1a, n1b;
    const float4 fz = (float4){0.f, 0.f, 0.f, 0.f};

    // ---- prologue ----
    {   // step 0 -> regs -> slot 0
        const float* p0 = Xb + (size_t)xrow0 * KF + xkc;
        o0a = *(const float4*)p0; o0b = *(const float4*)(p0 + 4);
        o1a = fz; o1b = fz;
        if (live1) {
            const float* p1 = Xb + (size_t)xrow1 * KF + xkc;
            o1a = *(const float4*)p1; o1b = *(const float4*)(p1 + 4);
        }
        bf16x8 v;
        v[0]=(bf16_t)o0a.x; v[1]=(bf16_t)o0a.y; v[2]=(bf16_t)o0a.z; v[3]=(bf16_t)o0a.w;
        v[4]=(bf16_t)o0b.x; v[5]=(bf16_t)o0b.y; v[6]=(bf16_t)o0b.z; v[7]=(bf16_t)o0b.w;
        *(bf16x8*)&Xs[xrow0 * XSTR + xkc] = v;
        if (has1) {
            bf16x8 v1;
            v1[0]=(bf16_t)o1a.x; v1[1]=(bf16_t)o1a.y; v1[2]=(bf16_t)o1a.z; v1[3]=(bf16_t)o1a.w;
            v1[4]=(bf16_t)o1b.x; v1[5]=(bf16_t)o1b.y; v1[6]=(bf16_t)o1b.z; v1[7]=(bf16_t)o1b.w;
            *(bf16x8*)&Xs[xrow1 * XSTR + xkc] = v1;
        }
        // step 1 -> O regs
        const float* q0 = Xb + (size_t)xrow0 * KF + 32 + xkc;
        o0a = *(const float4*)q0; o0b = *(const float4*)(q0 + 4);
        o1a = fz; o1b = fz;
        if (live1) {
            const float* q1 = Xb + (size_t)xrow1 * KF + 32 + xkc;
            o1a = *(const float4*)q1; o1b = *(const float4*)(q1 + 4);
        }
    }

    // ---- phase G ----
#pragma unroll 4
    for (int ks = 0; ks < 16; ++ks) {
        // issue loads for step ks+2
        if (ks + 2 < 16) {
            const int k2 = (ks + 2) * 32;
            const float* p0 = Xb + (size_t)xrow0 * KF + k2 + xkc;
            n0a = *(const float4*)p0; n0b = *(const float4*)(p0 + 4);
            n1a = fz; n1b = fz;
            if (live1) {
                const float* p1 = Xb + (size_t)xrow1 * KF + k2 + xkc;
                n1a = *(const float4*)p1; n1b = *(const float4*)(p1 + 4);
            }
        }
        // write step ks+1 (loaded last iter) into slot (ks+1)%4
        if (ks + 1 < 16) {
            bf16_t* Xn = Xs + ((ks + 1) & 3) * XSLOT;
            bf16x8 v;
            v[0]=(bf16_t)o0a.x; v[1]=(bf16_t)o0a.y; v[2]=(bf16_t)o0a.z; v[3]=(bf16_t)o0a.w;
            v[4]=(bf16_t)o0b.x; v[5]=(bf16_t)o0b.y; v[6]=(bf16_t)o0b.z; v[7]=(bf16_t)o0b.w;
            *(bf16x8*)&Xn[xrow0 * XSTR + xkc] = v;
            if (has1) {
                bf16x8 v1;
                v1[0]=(bf16_t)o1a.x; v1[1]=(bf16_t)o1a.y; v1[2]=(bf16_t)o1a.z; v1[3]=(bf16_t)o1a.w;
                v1[4]=(bf16_t)o1b.x; v1[5]=(bf16_t)o1b.y; v1[6]=(bf16_t)o1b.z; v1[7]=(bf16_t)o1b.w;
                *(bf16x8*)&Xn[xrow1 * XSTR + xkc] = v1;
            }
        }
        // W fragments for current step (L2-hot), issued pre-barrier
        bf16x8 wb[4];
        {
            const int k0 = ks * 32;
#pragma unroll
            for (int p = 0; p < 4; ++p)
                wb[p] = *(const bf16x8*)(Wt + (size_t)(w * 64 + p * 16 + lc) * KF + k0 + lr * 8);
        }
        __syncthreads();
        const bf16_t* Xc = Xs + (ks & 3) * XSLOT;
#pragma unroll
        for (int mt = 0; mt < 5; ++mt) {
            const bf16x8 af = *(const bf16x8*)&Xc[(mt * 16 + lc) * XSTR + lr * 8];
#pragma unroll
            for (int ntl = 0; ntl < 4; ++ntl)
                acc[mt][ntl] = __builtin_amdgcn_mfma_f32_16x16x32_bf16(af, wb[ntl], acc[mt][ntl], 0, 0, 0);
        }
        // rotate in-flight regs
        o0a = n0a; o0b = n0b; o1a = n1a; o1b = n1b;
    }
    __syncthreads();

    // ---- phase T: h stores, att partials, pack hbf ----
    float a0c[4], a1c[4];
#pragma unroll
    for (int ntl = 0; ntl < 4; ++ntl) {
        a0c[ntl] = a0s[w * 64 + ntl * 16 + lc];
        a1c[ntl] = a1s[w * 64 + ntl * 16 + lc];
    }
    float p0[5][4], p1[5][4];
#pragma unroll
    for (int mt = 0; mt < 5; ++mt)
#pragma unroll
        for (int j = 0; j < 4; ++j) { p0[mt][j] = 0.f; p1[mt][j] = 0.f; }

    bf16x4_t hbf[5][4];
#pragma unroll
    for (int mt = 0; mt < 5; ++mt) {
#pragma unroll
        for (int ntl = 0; ntl < 4; ++ntl) {
            const f32x4 v = acc[mt][ntl];
            const int ch = w * 64 + ntl * 16 + lc;
#pragma unroll
            for (int j = 0; j < 4; ++j) {
                const int row = mt * 16 + lr * 4 + j;
                if (row < NN) outb[(size_t)row * 512 + 256 + ch] = v[j];
                p0[mt][j] += v[j] * a0c[ntl];
                p1[mt][j] += v[j] * a1c[ntl];
            }
            bf16x4_t hv;
            hv[0] = (bf16_t)v[0]; hv[1] = (bf16_t)v[1];
            hv[2] = (bf16_t)v[2]; hv[3] = (bf16_t)v[3];
            hbf[mt][ntl] = hv;
        }
    }
#pragma unroll
    for (int off = 1; off < 16; off <<= 1) {
#pragma unroll
        for (int mt = 0; mt < 5; ++mt)
#pragma unroll
            for (int j = 0; j < 4; ++j) {
                p0[mt][j] += __shfl_xor(p0[mt][j], off);
                p1[mt][j] += __shfl_xor(p1[mt][j], off);
            }
    }
    if (lc == 0) {
#pragma unroll
        for (int mt = 0; mt < 5; ++mt)
#pragma unroll
            for (int j = 0; j < 4; ++j) {
                attp[w * 80 + mt * 16 + lr * 4 + j]       = p0[mt][j];
                attp[(4 + w) * 80 + mt * 16 + lr * 4 + j] = p1[mt][j];
            }
    }
    __syncthreads();

    // ---- phase 1b: wave-sum partials; zero alp pad region ----
    if (t < 80)
        att0s[t] = attp[t] + attp[80 + t] + attp[160 + t] + attp[240 + t];
    else if (t < 160)
        att1s[t - 80] = attp[320 + t - 80] + attp[400 + t - 80] + attp[480 + t - 80] + attp[560 + t - 80];
    else if (t < 240) {
        const int r = t - 160;
        if (r < NN) {
            for (int c = NN; c < 96; ++c) alp[r * ASTR + c] = (bf16_t)0.f;
        } else {
            for (int c = 0; c < 96; ++c) alp[r * ASTR + c] = (bf16_t)0.f;
        }
    }
    __syncthreads();

    // ---- phase S: 4-lane-group masked softmax (unnormalized) ----
    {
        const int gid = t >> 2;
        const int k4 = t & 3;
        for (int r = 0; r < 2; ++r) {
            const int i = r * 64 + gid;
            if (i < NN) {
                const float a0i = att0s[i];
                const u64 w0 = adjb[i * 2];
                const u64 w1 = adjb[i * 2 + 1];
                float e[19];
                float m = -3.0e38f;
#pragma unroll
                for (int jj = 0; jj < 19; ++jj) {
                    const int j = jj * 4 + k4;
                    float ev = -3.0e38f;
                    if (j < NN) {
                        float x = a0i + att1s[j];
                        x = x > 0.f ? x : 0.2f * x;
                        const u64 wj = (j < 64) ? w0 : w1;
                        const int bit = (int)((wj >> (j & 63)) & 1);
                        ev = bit ? x : x - 1.0e9f;
                    }
                    e[jj] = ev;
                    m = fmaxf(m, ev);
                }
                m = fmaxf(m, __shfl_xor(m, 1));
                m = fmaxf(m, __shfl_xor(m, 2));
                float s = 0.f;
#pragma unroll
                for (int jj = 0; jj < 19; ++jj) {
                    const int j = jj * 4 + k4;
                    if (j < NN) {
                        const float ex = __expf(e[jj] - m);
                        s += ex;
                        alp[i * ASTR + j] = (bf16_t)ex;
                    }
                }
                s += __shfl_xor(s, 1);
                s += __shfl_xor(s, 2);
                if (k4 == 0) rsums[i] = 1.f / s;
            }
        }
    }
    __syncthreads();

    // ---- phase P: out = (alp @ h) * rs via MFMA, 3 k-chunks ----
    f32x4 acc2[5][4];
#pragma unroll
    for (int i = 0; i < 5; ++i)
#pragma unroll
        for (int j = 0; j < 4; ++j) acc2[i][j] = (f32x4){0.f, 0.f, 0.f, 0.f};

#pragma unroll
    for (int kc = 0; kc < 3; ++kc) {
#pragma unroll
        for (int g = 0; g < 2; ++g) {
            const int mt = kc * 2 + g;
#pragma unroll
            for (int ntl = 0; ntl < 4; ++ntl) {
                const int ch = w * 64 + ntl * 16 + lc;
                bf16x4_t v;
                if (mt < 5) {
                    v = hbf[mt][ntl];
                } else {
                    v[0] = (bf16_t)0.f; v[1] = (bf16_t)0.f;
                    v[2] = (bf16_t)0.f; v[3] = (bf16_t)0.f;
                }
                *(bf16x4_t*)&hT[ch * HCH + g * 16 + lr * 4] = v;
            }
        }
        __syncthreads();
        bf16x8 bv[4];
#pragma unroll
        for (int ntl = 0; ntl < 4; ++ntl)
            bv[ntl] = *(const bf16x8*)&hT[(w * 64 + ntl * 16 + lc) * HCH + lr * 8];
#pragma unroll
        for (int mt = 0; mt < 5; ++mt) {
            const bf16_t* ap = &alp[(mt * 16 + lc) * ASTR + kc * 32 + lr * 8];
            bf16x8 av;
            ((uint2*)&av)[0] = *(const uint2*)ap;
            ((uint2*)&av)[1] = *(const uint2*)(ap + 4);
#pragma unroll
            for (int ntl = 0; ntl < 4; ++ntl)
                acc2[mt][ntl] = __builtin_amdgcn_mfma_f32_16x16x32_bf16(av, bv[ntl], acc2[mt][ntl], 0, 0, 0);
        }
        if (kc < 2) __syncthreads();
    }

    // epilogue: scale by 1/s and store
#pragma unroll
    for (int mt = 0; mt < 5; ++mt) {
        float rsv[4];
#pragma unroll
        for (int j = 0; j < 4; ++j) {
            const int row = mt * 16 + lr * 4 + j;
            rsv[j] = (row < NN) ? rsums[row] : 0.f;
        }
#pragma unroll
        for (int ntl = 0; ntl < 4; ++ntl) {
            const int ch = w * 64 + ntl * 16 + lc;
#pragma unroll
            for (int j = 0; j < 4; ++j) {
                const int row = mt * 16 + lr * 4 + j;
                if (row < NN) outb[(size_t)row * 512 + ch] = acc2[mt][ntl][j] * rsv[j];
            }
        }
    }
}

// ---------------------------------------------------------------------------
extern "C" void kernel_launch(void* const* d_in, const int* in_sizes, int n_in,
                              void* d_out, int out_size, void* d_ws, size_t ws_size,
                              hipStream_t stream) {
    const float* X = (const float*)d_in[0];   // [1024,75,512] f32
    const int*   A = (const int*)d_in[1];     // [75,75] i32
    const float* W = (const float*)d_in[2];   // [512,256] f32
    const float* a = (const float*)d_in[3];   // [2,256,1] f32
    float* out = (float*)d_out;               // [1024,75,512] f32
    bf16_t* Wt = (bf16_t*)d_ws;               // 256 KB scratch

    wt_kernel<<<dim3(KF / 64, F1 / 64), 256, 0, stream>>>(W, Wt);
    fused_kernel<<<NB, 256, 0, stream>>>(X, Wt, A, a, out);
}

// Round 8
// 136.654 us; speedup vs baseline: 1.9532x; 1.1680x over previous
//
#include <hip/hip_runtime.h>
#include <hip/hip_bf16.h>
#include <math.h>

typedef __bf16 bf16_t;
typedef __bf16 bf16x4_t __attribute__((ext_vector_type(4)));
typedef __bf16 bf16x8 __attribute__((ext_vector_type(8)));
typedef float f32x4 __attribute__((ext_vector_type(4)));
typedef unsigned long long u64;

#define NB 1024
#define NN 75
#define KF 512
#define F1 256
#define HSTR 100   // hT row stride (bf16): 8B-aligned rows, 16 distinct bank starts
#define ASTR 100   // alp row stride

// ---------------------------------------------------------------------------
// Kernel 0: W [512][256] fp32 -> Wt [256][512] bf16 (transposed, k-contiguous)
// (round-0/1 exact, passing since round 1)
// ---------------------------------------------------------------------------
__global__ __launch_bounds__(256) void wt_kernel(const float* __restrict__ W,
                                                 bf16_t* __restrict__ Wt) {
    __shared__ float tile[64][65];
    const int kb = blockIdx.x * 64;
    const int nb = blockIdx.y * 64;
    const int tc = threadIdx.x & 63;
    const int tr = threadIdx.x >> 6;
#pragma unroll
    for (int r = tr; r < 64; r += 4)
        tile[r][tc] = W[(size_t)(kb + r) * F1 + nb + tc];
    __syncthreads();
#pragma unroll
    for (int r = tr; r < 64; r += 4)
        Wt[(size_t)(nb + r) * KF + kb + tc] = (bf16_t)tile[tc][r];
}

// ---------------------------------------------------------------------------
// Kernel 1: h = X @ W -> out[...,256:512]. EXACT round-1 body (passed).
// ---------------------------------------------------------------------------
__global__ __launch_bounds__(256) void gemm_kernel(const float* __restrict__ X,
                                                   const bf16_t* __restrict__ Wt,
                                                   float* __restrict__ out) {
    __shared__ __align__(16) bf16_t Asm[64 * 32];
    __shared__ __align__(16) bf16_t Bsm[256 * 32];
    const int t = threadIdx.x;
    const int w = t >> 6;
    const int l = t & 63;
    const int m0 = blockIdx.x * 64;

    f32x4 acc[16];
#pragma unroll
    for (int i = 0; i < 16; ++i) acc[i] = (f32x4){0.f, 0.f, 0.f, 0.f};

    const int ar = t >> 2;
    const int ak = (t & 3) * 8;
    const float* xptr = X + (size_t)(m0 + ar) * KF + ak;

    const int koff = (l >> 4) * 8;
    const bf16_t* afrag_p = &Asm[(w * 16 + (l & 15)) * 32 + koff];
    const bf16_t* bfrag_p = &Bsm[(l & 15) * 32 + koff];

    for (int ks = 0; ks < 16; ++ks) {
        const int k0 = ks * 32;
        const float4 x0 = *(const float4*)(xptr + k0);
        const float4 x1 = *(const float4*)(xptr + k0 + 4);
        bf16x8 av;
        av[0] = (bf16_t)x0.x; av[1] = (bf16_t)x0.y;
        av[2] = (bf16_t)x0.z; av[3] = (bf16_t)x0.w;
        av[4] = (bf16_t)x1.x; av[5] = (bf16_t)x1.y;
        av[6] = (bf16_t)x1.z; av[7] = (bf16_t)x1.w;
        *(bf16x8*)&Asm[ar * 32 + ak] = av;
#pragma unroll
        for (int p = 0; p < 4; ++p) {
            const int row = p * 64 + ar;
            *(uint4*)&Bsm[row * 32 + ak] =
                *(const uint4*)(Wt + (size_t)row * KF + k0 + ak);
        }
        __syncthreads();
        const bf16x8 af = *(const bf16x8*)afrag_p;
#pragma unroll
        for (int nt = 0; nt < 16; ++nt) {
            const bf16x8 bfv = *(const bf16x8*)(bfrag_p + nt * 16 * 32);
            acc[nt] = __builtin_amdgcn_mfma_f32_16x16x32_bf16(af, bfv, acc[nt], 0, 0, 0);
        }
        __syncthreads();
    }

    const int mrow = m0 + w * 16 + (l >> 4) * 4;
    const int ncol = l & 15;
#pragma unroll
    for (int nt = 0; nt < 16; ++nt) {
#pragma unroll
        for (int j = 0; j < 4; ++j) {
            out[(size_t)(mrow + j) * 512 + 256 + nt * 16 + ncol] = acc[nt][j];
        }
    }
}

// ---------------------------------------------------------------------------
// Kernel 2: per-batch attention, fully self-contained (no att transport).
//  phase T: round-2 exact — load h[b] rows (f32 from out), fused att dot
//           partials, 4x4 register transpose -> hT bf16 [256][HSTR]
//  phase 1b: round-5 exact — cross-wave att sums, alp pad-row zeroing
//  phase S: round-5 exact — 4-lane-group masked softmax, unnormalized alp
//  phase P: round-5 read patterns on full hT (uint2-pair frag loads),
//           deferred 1/s in epilogue
// ---------------------------------------------------------------------------
__global__ __launch_bounds__(256) void pv_kernel(const int* __restrict__ Adj,
                                                 const float* __restrict__ avec,
                                                 float* __restrict__ out) {
    __shared__ __align__(16) bf16_t hT[256 * HSTR];   // 51200 B
    __shared__ __align__(16) bf16_t alp[80 * ASTR];   // 16000 B
    __shared__ float a0s[F1], a1s[F1];
    __shared__ float attp0[4][80], attp1[4][80];
    __shared__ float att0s[80], att1s[80], rsums[80];
    __shared__ u64 adjb[160];

    const int b = blockIdx.x;
    const int t = threadIdx.x;
    const int w = t >> 6;
    const int l = t & 63;
    const int lc = l & 15;
    const int lr = l >> 4;
    float* outb = out + (size_t)b * NN * 512;

    // ---- phase 0: a-vectors, adjacency bitmask, hT k-pad zero ----
    a0s[t] = avec[t];
    a1s[t] = avec[F1 + t];
    for (int i = w; i < NN; i += 4) {
        const int v0 = Adj[i * NN + l];
        const int v1 = (l < NN - 64) ? Adj[i * NN + 64 + l] : 0;
        const u64 b0 = __ballot(v0 != 0);
        const u64 b1 = __ballot(v1 != 0);
        if (l == 0) { adjb[i * 2] = b0; adjb[i * 2 + 1] = b1; }
    }
    {
        int* z = (int*)&hT[t * HSTR + 80];   // cols 80..95 of row t
#pragma unroll
        for (int k = 0; k < 8; ++k) z[k] = 0;
    }
    __syncthreads();

    // ---- phase T: load h + att partials + transpose (round-2 exact) ----
    const int c0 = w * 64 + lc * 4;
    const float4 a04 = *(const float4*)&a0s[c0];
    const float4 a14 = *(const float4*)&a1s[c0];
#pragma unroll
    for (int jp = 0; jp < 5; ++jp) {
        const int j0 = jp * 16 + lr * 4;
        float hr[4][4];
#pragma unroll
        for (int r = 0; r < 4; ++r) {
            if (j0 + r < NN) {
                const float4 v = *(const float4*)(outb + (size_t)(j0 + r) * 512 + 256 + c0);
                hr[r][0] = v.x; hr[r][1] = v.y; hr[r][2] = v.z; hr[r][3] = v.w;
            } else {
                hr[r][0] = hr[r][1] = hr[r][2] = hr[r][3] = 0.f;
            }
        }
        float p0[4], p1[4];
#pragma unroll
        for (int r = 0; r < 4; ++r) {
            p0[r] = hr[r][0] * a04.x + hr[r][1] * a04.y + hr[r][2] * a04.z + hr[r][3] * a04.w;
            p1[r] = hr[r][0] * a14.x + hr[r][1] * a14.y + hr[r][2] * a14.z + hr[r][3] * a14.w;
        }
#pragma unroll
        for (int off = 1; off < 16; off <<= 1) {
#pragma unroll
            for (int r = 0; r < 4; ++r) {
                p0[r] += __shfl_xor(p0[r], off);
                p1[r] += __shfl_xor(p1[r], off);
            }
        }
        if (lc == 0) {
#pragma unroll
            for (int r = 0; r < 4; ++r) {
                attp0[w][j0 + r] = p0[r];
                attp1[w][j0 + r] = p1[r];
            }
        }
#pragma unroll
        for (int cc = 0; cc < 4; ++cc) {
            bf16x4_t v;
            v[0] = (bf16_t)hr[0][cc]; v[1] = (bf16_t)hr[1][cc];
            v[2] = (bf16_t)hr[2][cc]; v[3] = (bf16_t)hr[3][cc];
            *(bf16x4_t*)&hT[(c0 + cc) * HSTR + j0] = v;
        }
    }
    __syncthreads();

    // ---- phase 1b: cross-wave att sums; zero alp pad rows (round-5 exact) ----
    if (t < 80)
        att0s[t] = attp0[0][t] + attp0[1][t] + attp0[2][t] + attp0[3][t];
    else if (t < 160)
        att1s[t - 80] = attp1[0][t - 80] + attp1[1][t - 80] + attp1[2][t - 80] + attp1[3][t - 80];
    else if (t < 240) {
        const int r = t - 160;
        if (r < NN) {
            for (int c = NN; c < 96; ++c) alp[r * ASTR + c] = (bf16_t)0.f;
        } else {
            for (int c = 0; c < 96; ++c) alp[r * ASTR + c] = (bf16_t)0.f;
        }
    }
    __syncthreads();

    // ---- phase S: 4-lane-group masked softmax (round-5 exact) ----
    {
        const int gid = t >> 2;
        const int k4 = t & 3;
#pragma unroll
        for (int r = 0; r < 2; ++r) {
            const int i = r * 64 + gid;
            if (i < NN) {
                const float a0i = att0s[i];
                const u64 w0 = adjb[i * 2];
                const u64 w1 = adjb[i * 2 + 1];
                float e[19];
                float m = -3.0e38f;
#pragma unroll
                for (int jj = 0; jj < 19; ++jj) {
                    const int j = jj * 4 + k4;
                    float ev = -3.0e38f;
                    if (j < NN) {
                        float x = a0i + att1s[j];
                        x = x > 0.f ? x : 0.2f * x;
                        const u64 wj = (j < 64) ? w0 : w1;
                        const int bit = (int)((wj >> (j & 63)) & 1);
                        ev = bit ? x : x - 1.0e9f;
                    }
                    e[jj] = ev;
                    m = fmaxf(m, ev);
                }
                m = fmaxf(m, __shfl_xor(m, 1));
                m = fmaxf(m, __shfl_xor(m, 2));
                float s = 0.f;
#pragma unroll
                for (int jj = 0; jj < 19; ++jj) {
                    const int j = jj * 4 + k4;
                    if (j < NN) {
                        const float ex = __expf(e[jj] - m);
                        s += ex;
                        alp[i * ASTR + j] = (bf16_t)ex;
                    }
                }
                s += __shfl_xor(s, 1);
                s += __shfl_xor(s, 2);
                if (k4 == 0) rsums[i] = 1.f / s;
            }
        }
    }
    __syncthreads();

    // ---- phase P: out[i][ch] = (sum_j alp[i][j] hT[ch][j]) * rs via MFMA ----
    f32x4 acc2[5][4];
#pragma unroll
    for (int i = 0; i < 5; ++i)
#pragma unroll
        for (int j = 0; j < 4; ++j) acc2[i][j] = (f32x4){0.f, 0.f, 0.f, 0.f};

#pragma unroll
    for (int ks = 0; ks < 3; ++ks) {
        bf16x8 bv[4];
#pragma unroll
        for (int ntl = 0; ntl < 4; ++ntl) {
            const bf16_t* q = &hT[(w * 64 + ntl * 16 + lc) * HSTR + ks * 32 + lr * 8];
            ((uint2*)&bv[ntl])[0] = *(const uint2*)q;
            ((uint2*)&bv[ntl])[1] = *(const uint2*)(q + 4);
        }
#pragma unroll
        for (int mt = 0; mt < 5; ++mt) {
            const bf16_t* ap = &alp[(mt * 16 + lc) * ASTR + ks * 32 + lr * 8];
            bf16x8 av;
            ((uint2*)&av)[0] = *(const uint2*)ap;
            ((uint2*)&av)[1] = *(const uint2*)(ap + 4);
#pragma unroll
            for (int ntl = 0; ntl < 4; ++ntl)
                acc2[mt][ntl] = __builtin_amdgcn_mfma_f32_16x16x32_bf16(av, bv[ntl], acc2[mt][ntl], 0, 0, 0);
        }
    }

    // ---- epilogue: scale by 1/s, store ch 0..255 (round-5 exact) ----
#pragma unroll
    for (int mt = 0; mt < 5; ++mt) {
#pragma unroll
        for (int j = 0; j < 4; ++j) {
            const int row = mt * 16 + lr * 4 + j;
            if (row < NN) {
                const float rsv = rsums[row];
#pragma unroll
                for (int ntl = 0; ntl < 4; ++ntl) {
                    const int ch = w * 64 + ntl * 16 + lc;
                    outb[(size_t)row * 512 + ch] = acc2[mt][ntl][j] * rsv;
                }
            }
        }
    }
}

// ---------------------------------------------------------------------------
extern "C" void kernel_launch(void* const* d_in, const int* in_sizes, int n_in,
                              void* d_out, int out_size, void* d_ws, size_t ws_size,
                              hipStream_t stream) {
    const float* X = (const float*)d_in[0];   // [1024,75,512] f32
    const int*   A = (const int*)d_in[1];     // [75,75] i32
    const float* W = (const float*)d_in[2];   // [512,256] f32
    const float* a = (const float*)d_in[3];   // [2,256,1] f32
    float* out = (float*)d_out;               // [1024,75,512] f32
    bf16_t* Wt = (bf16_t*)d_ws;               // 256 KB scratch

    wt_kernel<<<dim3(KF / 64, F1 / 64), 256, 0, stream>>>(W, Wt);
    gemm_kernel<<<(NB * NN) / 64, 256, 0, stream>>>(X, Wt, out);
    pv_kernel<<<NB, 256, 0, stream>>>(A, a, out);
}